// Round 2
// baseline (698.794 us; speedup 1.0000x reference)
//
#include <hip/hip_runtime.h>

#define DIMK 512
#define NCH  8192
#define MTOT 4096   // BATCH*SEQ = 2*2048
#define SEQL 2048

typedef __attribute__((ext_vector_type(8))) short bf16x8;
typedef __attribute__((ext_vector_type(4))) float f32x4;

__device__ __forceinline__ unsigned short f2bf(float f) {
  unsigned int u = __float_as_uint(f);
  u += 0x7fffu + ((u >> 16) & 1u);
  return (unsigned short)(u >> 16);
}
__device__ __forceinline__ float bf2f(unsigned short v) {
  return __uint_as_float(((unsigned int)v) << 16);
}

// ---------------- f32 -> bf16 convert (8 elems/thread) ----------------
__global__ __launch_bounds__(256) void cvt_kernel(const float* __restrict__ src,
                                                  unsigned short* __restrict__ dst,
                                                  int n8) {
  int i = blockIdx.x * 256 + threadIdx.x;
  if (i >= n8) return;
  const float4* s = reinterpret_cast<const float4*>(src);
  float4 a = s[2 * i], b = s[2 * i + 1];
  union { unsigned short us[8]; uint4 v; } o;
  o.us[0] = f2bf(a.x); o.us[1] = f2bf(a.y); o.us[2] = f2bf(a.z); o.us[3] = f2bf(a.w);
  o.us[4] = f2bf(b.x); o.us[5] = f2bf(b.y); o.us[6] = f2bf(b.z); o.us[7] = f2bf(b.w);
  reinterpret_cast<uint4*>(dst)[i] = o.v;
}

// ---------------- fused 4-way projection GEMM + SSM epilogue ----------------
// xb [rows][512] bf16 (chunk base), w4 [4][8192][512] bf16 (dt,B,C,V)
// per block: BM=128 (m), BN=64 (n) for ALL FOUR projections, BK=32.
#define PLDS_A 4096            // 128*32 elems
#define PLDS_W 8192            // 4*64*32 elems
__global__ __launch_bounds__(256) void proj_kernel(
    const unsigned short* __restrict__ xb,
    const unsigned short* __restrict__ w4,
    const float* __restrict__ b_dt, const float* __restrict__ b_B,
    const float* __restrict__ b_C, const float* __restrict__ b_V,
    const float* __restrict__ A_log,
    unsigned short* __restrict__ vlog,   // [rows][8192] bf16: dt*A_log
    unsigned short* __restrict__ u_out,  // [rows][8192] bf16: dt*zB*zV
    unsigned short* __restrict__ c_out)  // [rows][8192] bf16: zC
{
  __shared__ __align__(16) unsigned short lds[2][PLDS_A + PLDS_W];
  const int tid = threadIdx.x;
  const int lane = tid & 63;
  const int wave = tid >> 6;
  const int wr = wave >> 1, wc = wave & 1;
  const int n0 = blockIdx.x * 64;
  const int m0 = blockIdx.y * 128;

  auto stage = [&](int buf, int kt) {
    const int k0 = kt * 32;
    #pragma unroll
    for (int i = 0; i < 2; ++i) {            // A tile: 128x32 = 8KB
      int c = i * 256 + tid;
      int row = c >> 2, q = c & 3;
      const unsigned short* g = xb + (size_t)(m0 + row) * DIMK + k0 + q * 8;
      __builtin_amdgcn_global_load_lds(
          (const __attribute__((address_space(1))) void*)g,
          (__attribute__((address_space(3))) void*)&lds[buf][c * 8], 16, 0, 0);
    }
    #pragma unroll
    for (int p = 0; p < 4; ++p) {            // W tiles: 4 x 64x32 = 16KB
      int row = tid >> 2, q = tid & 3;
      const unsigned short* g = w4 + ((size_t)p * NCH + n0 + row) * DIMK + k0 + q * 8;
      __builtin_amdgcn_global_load_lds(
          (const __attribute__((address_space(1))) void*)g,
          (__attribute__((address_space(3))) void*)&lds[buf][PLDS_A + p * 2048 + tid * 8], 16, 0, 0);
    }
  };

  f32x4 acc[4][4][2];
  #pragma unroll
  for (int p = 0; p < 4; ++p)
    #pragma unroll
    for (int fm = 0; fm < 4; ++fm)
      #pragma unroll
      for (int fn = 0; fn < 2; ++fn)
        acc[p][fm][fn] = (f32x4){0.f, 0.f, 0.f, 0.f};

  stage(0, 0);
  __syncthreads();
  #pragma unroll 1
  for (int kt = 0; kt < DIMK / 32; ++kt) {
    const int buf = kt & 1;
    if (kt + 1 < DIMK / 32) stage(buf ^ 1, kt + 1);
    bf16x8 af[4];
    #pragma unroll
    for (int fm = 0; fm < 4; ++fm)
      af[fm] = *reinterpret_cast<const bf16x8*>(
          &lds[buf][(wr * 64 + fm * 16 + (lane & 15)) * 32 + (lane >> 4) * 8]);
    #pragma unroll
    for (int p = 0; p < 4; ++p) {
      bf16x8 bfr[2];
      #pragma unroll
      for (int fn = 0; fn < 2; ++fn)
        bfr[fn] = *reinterpret_cast<const bf16x8*>(
            &lds[buf][PLDS_A + p * 2048 + (wc * 32 + fn * 16 + (lane & 15)) * 32 + (lane >> 4) * 8]);
      #pragma unroll
      for (int fm = 0; fm < 4; ++fm)
        #pragma unroll
        for (int fn = 0; fn < 2; ++fn)
          acc[p][fm][fn] = __builtin_amdgcn_mfma_f32_16x16x32_bf16(
              af[fm], bfr[fn], acc[p][fm][fn], 0, 0, 0);
    }
    __syncthreads();
  }

  // epilogue: dt = softplus(zdt); vlog = dt*A_log; u = dt*zB*zV; c = zC
  #pragma unroll
  for (int fn = 0; fn < 2; ++fn) {
    const int n = n0 + wc * 32 + fn * 16 + (lane & 15);
    const float vbdt = b_dt[n], vbB = b_B[n], vbC = b_C[n], vbV = b_V[n];
    const float al = A_log[n];
    #pragma unroll
    for (int fm = 0; fm < 4; ++fm) {
      const int mbase = m0 + wr * 64 + fm * 16 + (lane >> 4) * 4;
      #pragma unroll
      for (int r = 0; r < 4; ++r) {
        const size_t off = (size_t)(mbase + r) * NCH + n;
        const float zdt = acc[0][fm][fn][r] + vbdt;
        const float zB  = acc[1][fm][fn][r] + vbB;
        const float zC  = acc[2][fm][fn][r] + vbC;
        const float zV  = acc[3][fm][fn][r] + vbV;
        const float dt = (zdt > 15.f) ? zdt : __logf(1.f + __expf(zdt));
        vlog[off]  = f2bf(dt * al);
        u_out[off] = f2bf(dt * zB * zV);
        c_out[off] = f2bf(zC);
      }
    }
  }
}

// ---------------- sequential scan over s, one thread per channel ----------------
// cy holds C on input, y on output (in-place, same pointer: per-thread RAW order).
__global__ __launch_bounds__(64) void scan_kernel(
    const unsigned short* __restrict__ vlog, const unsigned short* __restrict__ u_in,
    unsigned short* cy, float* hstate, int use_state, int seqlen)
{
  const int n = blockIdx.x * 64 + threadIdx.x;          // 0..8191
  const size_t base = (size_t)blockIdx.y * ((size_t)seqlen * NCH) + n;
  const unsigned short* ap = vlog + base;
  const unsigned short* up = u_in + base;
  unsigned short* cp = cy + base;
  float h = use_state ? hstate[n] : 0.f;
  constexpr int U = 16;
  #pragma unroll 1
  for (int s0 = 0; s0 < seqlen; s0 += U) {
    float a[U], uu[U], cc[U];
    #pragma unroll
    for (int i = 0; i < U; ++i) {
      const size_t o = (size_t)(s0 + i) * NCH;
      a[i]  = __expf(bf2f(ap[o]));
      uu[i] = bf2f(up[o]);
      cc[i] = bf2f(cp[o]);
    }
    #pragma unroll
    for (int i = 0; i < U; ++i) {
      h = fmaf(a[i], h, uu[i]);
      cc[i] *= h;
    }
    #pragma unroll
    for (int i = 0; i < U; ++i) cp[(size_t)(s0 + i) * NCH] = f2bf(cc[i]);
  }
  if (blockIdx.y == gridDim.y - 1) hstate[n] = h;
}

// ---------------- output projection: out[m][d] = sum_n y[m][n]*Wout[d][n] + b[d]
#define OLDS_A 4096   // 128*32
#define OLDS_B 2048   // 64*32
__global__ __launch_bounds__(256) void outproj_kernel(
    const unsigned short* __restrict__ yb,    // [rows][8192] bf16
    const unsigned short* __restrict__ wout,  // [512][8192] bf16
    const float* __restrict__ bias,           // [512]
    float* __restrict__ out)                  // [rows][512] f32
{
  __shared__ __align__(16) unsigned short lds[2][OLDS_A + OLDS_B];
  const int tid = threadIdx.x;
  const int lane = tid & 63;
  const int wave = tid >> 6;
  const int wr = wave >> 1, wc = wave & 1;
  const int d0 = blockIdx.x * 64;
  const int m0 = blockIdx.y * 128;

  auto stage = [&](int buf, int kt) {
    const int k0 = kt * 32;
    #pragma unroll
    for (int i = 0; i < 2; ++i) {
      int c = i * 256 + tid;
      int row = c >> 2, q = c & 3;
      const unsigned short* g = yb + (size_t)(m0 + row) * NCH + k0 + q * 8;
      __builtin_amdgcn_global_load_lds(
          (const __attribute__((address_space(1))) void*)g,
          (__attribute__((address_space(3))) void*)&lds[buf][c * 8], 16, 0, 0);
    }
    {
      int row = tid >> 2, q = tid & 3;
      const unsigned short* g = wout + (size_t)(d0 + row) * NCH + k0 + q * 8;
      __builtin_amdgcn_global_load_lds(
          (const __attribute__((address_space(1))) void*)g,
          (__attribute__((address_space(3))) void*)&lds[buf][OLDS_A + tid * 8], 16, 0, 0);
    }
  };

  f32x4 acc[4][2];
  #pragma unroll
  for (int fm = 0; fm < 4; ++fm)
    #pragma unroll
    for (int fn = 0; fn < 2; ++fn) acc[fm][fn] = (f32x4){0.f, 0.f, 0.f, 0.f};

  stage(0, 0);
  __syncthreads();
  #pragma unroll 1
  for (int kt = 0; kt < NCH / 32; ++kt) {
    const int buf = kt & 1;
    if (kt + 1 < NCH / 32) stage(buf ^ 1, kt + 1);
    bf16x8 af[4], bfr[2];
    #pragma unroll
    for (int fm = 0; fm < 4; ++fm)
      af[fm] = *reinterpret_cast<const bf16x8*>(
          &lds[buf][(wr * 64 + fm * 16 + (lane & 15)) * 32 + (lane >> 4) * 8]);
    #pragma unroll
    for (int fn = 0; fn < 2; ++fn)
      bfr[fn] = *reinterpret_cast<const bf16x8*>(
          &lds[buf][OLDS_A + (wc * 32 + fn * 16 + (lane & 15)) * 32 + (lane >> 4) * 8]);
    #pragma unroll
    for (int fm = 0; fm < 4; ++fm)
      #pragma unroll
      for (int fn = 0; fn < 2; ++fn)
        acc[fm][fn] = __builtin_amdgcn_mfma_f32_16x16x32_bf16(
            af[fm], bfr[fn], acc[fm][fn], 0, 0, 0);
    __syncthreads();
  }

  #pragma unroll
  for (int fn = 0; fn < 2; ++fn) {
    const int d = d0 + wc * 32 + fn * 16 + (lane & 15);
    const float bd = bias[d];
    #pragma unroll
    for (int fm = 0; fm < 4; ++fm) {
      const int mbase = m0 + wr * 64 + fm * 16 + (lane >> 4) * 4;
      #pragma unroll
      for (int r = 0; r < 4; ++r)
        out[(size_t)(mbase + r) * DIMK + d] = acc[fm][fn][r] + bd;
    }
  }
}

extern "C" void kernel_launch(void* const* d_in, const int* in_sizes, int n_in,
                              void* d_out, int out_size, void* d_ws, size_t ws_size,
                              hipStream_t stream) {
  const float* x    = (const float*)d_in[0];
  const float* Wdt  = (const float*)d_in[1];
  const float* bdt  = (const float*)d_in[2];
  const float* WB   = (const float*)d_in[3];
  const float* bB   = (const float*)d_in[4];
  const float* WC   = (const float*)d_in[5];
  const float* bC   = (const float*)d_in[6];
  const float* WV   = (const float*)d_in[7];
  const float* bV   = (const float*)d_in[8];
  const float* Alog = (const float*)d_in[9];
  const float* Wout = (const float*)d_in[10];
  const float* bout = (const float*)d_in[11];
  float* out = (float*)d_out;

  char* ws = (char*)d_ws;
  unsigned short* woutb = (unsigned short*)(ws);               // 8 MB
  unsigned short* xb    = (unsigned short*)(ws + 8388608);     // 4 MB
  unsigned short* w4    = (unsigned short*)(ws + 12582912);    // 32 MB
  char* dyn = ws + 46137344;

  // workspace-adaptive chunking (ws_size constant per session -> graph-safe)
  int chunk_rows;
  if (ws_size >= 247529472ULL)      chunk_rows = 4096;  // full, 247.5 MB
  else if (ws_size >= 146866176ULL) chunk_rows = 2048;  // per-batch, 146.9 MB
  else                              chunk_rows = 1024;  // seq-chunks+carry, 96.5 MB
  const size_t csz = (size_t)chunk_rows * NCH * 2;
  unsigned short* vlog = (unsigned short*)(dyn);
  unsigned short* u_b  = (unsigned short*)(dyn + csz);
  unsigned short* cy   = (unsigned short*)(dyn + 2 * csz);
  float*          hst  = (float*)(dyn + 3 * csz);             // 64 KB (carry)

  // bf16 conversions (once)
  cvt_kernel<<<1024, 256, 0, stream>>>(x, xb, 262144);
  cvt_kernel<<<2048, 256, 0, stream>>>(Wdt, w4 + 0 * 4194304, 524288);
  cvt_kernel<<<2048, 256, 0, stream>>>(WB,  w4 + 1 * 4194304, 524288);
  cvt_kernel<<<2048, 256, 0, stream>>>(WC,  w4 + 2 * 4194304, 524288);
  cvt_kernel<<<2048, 256, 0, stream>>>(WV,  w4 + 3 * 4194304, 524288);
  cvt_kernel<<<2048, 256, 0, stream>>>(Wout, woutb, 524288);

  for (int m0 = 0; m0 < MTOT; m0 += chunk_rows) {
    proj_kernel<<<dim3(NCH / 64, chunk_rows / 128), 256, 0, stream>>>(
        xb + (size_t)m0 * DIMK, w4, bdt, bB, bC, bV, Alog, vlog, u_b, cy);
    const int seqlen = (chunk_rows <= SEQL) ? chunk_rows : SEQL;
    const int nseq = chunk_rows / seqlen;
    const int use_state = (m0 % SEQL) != 0;
    scan_kernel<<<dim3(NCH / 64, nseq), 64, 0, stream>>>(
        vlog, u_b, cy, hst, use_state, seqlen);
    outproj_kernel<<<dim3(DIMK / 64, chunk_rows / 128), 256, 0, stream>>>(
        cy, woutb, bout, out + (size_t)m0 * DIMK);
  }
}

// Round 3
// 594.268 us; speedup vs baseline: 1.1759x; 1.1759x over previous
//
#include <hip/hip_runtime.h>

#define DIMK 512
#define NCH  8192
#define MTOT 4096   // BATCH*SEQ = 2*2048
#define SEQL 2048
#define KS   8      // outproj K-splits

typedef __attribute__((ext_vector_type(8))) short bf16x8;
typedef __attribute__((ext_vector_type(4))) float f32x4;

__device__ __forceinline__ unsigned short f2bf(float f) {
  unsigned int u = __float_as_uint(f);
  u += 0x7fffu + ((u >> 16) & 1u);
  return (unsigned short)(u >> 16);
}
__device__ __forceinline__ float bf2f(unsigned short v) {
  return __uint_as_float(((unsigned int)v) << 16);
}

// ---------------- f32 -> bf16 convert (8 elems/thread) ----------------
__global__ __launch_bounds__(256) void cvt_kernel(const float* __restrict__ src,
                                                  unsigned short* __restrict__ dst,
                                                  int n8) {
  int i = blockIdx.x * 256 + threadIdx.x;
  if (i >= n8) return;
  const float4* s = reinterpret_cast<const float4*>(src);
  float4 a = s[2 * i], b = s[2 * i + 1];
  union { unsigned short us[8]; uint4 v; } o;
  o.us[0] = f2bf(a.x); o.us[1] = f2bf(a.y); o.us[2] = f2bf(a.z); o.us[3] = f2bf(a.w);
  o.us[4] = f2bf(b.x); o.us[5] = f2bf(b.y); o.us[6] = f2bf(b.z); o.us[7] = f2bf(b.w);
  reinterpret_cast<uint4*>(dst)[i] = o.v;
}

// ---------------- fused 4-way projection GEMM + SSM epilogue ----------------
#define PLDS_A 4096            // 128*32 elems
#define PLDS_W 8192            // 4*64*32 elems
__global__ __launch_bounds__(256) void proj_kernel(
    const unsigned short* __restrict__ xb,
    const unsigned short* __restrict__ w4,
    const float* __restrict__ b_dt, const float* __restrict__ b_B,
    const float* __restrict__ b_C, const float* __restrict__ b_V,
    const float* __restrict__ A_log,
    unsigned short* __restrict__ vlog,   // [rows][8192] bf16: dt*A_log
    unsigned short* __restrict__ u_out,  // [rows][8192] bf16: dt*zB*zV
    unsigned short* __restrict__ c_out)  // [rows][8192] bf16: zC
{
  __shared__ __align__(16) unsigned short lds[2][PLDS_A + PLDS_W];
  const int tid = threadIdx.x;
  const int lane = tid & 63;
  const int wave = tid >> 6;
  const int wr = wave >> 1, wc = wave & 1;
  const int n0 = blockIdx.x * 64;
  const int m0 = blockIdx.y * 128;

  auto stage = [&](int buf, int kt) {
    const int k0 = kt * 32;
    #pragma unroll
    for (int i = 0; i < 2; ++i) {            // A tile: 128x32 = 8KB
      int c = i * 256 + tid;
      int row = c >> 2, q = c & 3;
      const unsigned short* g = xb + (size_t)(m0 + row) * DIMK + k0 + q * 8;
      __builtin_amdgcn_global_load_lds(
          (const __attribute__((address_space(1))) void*)g,
          (__attribute__((address_space(3))) void*)&lds[buf][c * 8], 16, 0, 0);
    }
    #pragma unroll
    for (int p = 0; p < 4; ++p) {            // W tiles: 4 x 64x32 = 16KB
      int row = tid >> 2, q = tid & 3;
      const unsigned short* g = w4 + ((size_t)p * NCH + n0 + row) * DIMK + k0 + q * 8;
      __builtin_amdgcn_global_load_lds(
          (const __attribute__((address_space(1))) void*)g,
          (__attribute__((address_space(3))) void*)&lds[buf][PLDS_A + p * 2048 + tid * 8], 16, 0, 0);
    }
  };

  f32x4 acc[4][4][2];
  #pragma unroll
  for (int p = 0; p < 4; ++p)
    #pragma unroll
    for (int fm = 0; fm < 4; ++fm)
      #pragma unroll
      for (int fn = 0; fn < 2; ++fn)
        acc[p][fm][fn] = (f32x4){0.f, 0.f, 0.f, 0.f};

  stage(0, 0);
  __syncthreads();
  #pragma unroll 1
  for (int kt = 0; kt < DIMK / 32; ++kt) {
    const int buf = kt & 1;
    if (kt + 1 < DIMK / 32) stage(buf ^ 1, kt + 1);
    bf16x8 af[4];
    #pragma unroll
    for (int fm = 0; fm < 4; ++fm)
      af[fm] = *reinterpret_cast<const bf16x8*>(
          &lds[buf][(wr * 64 + fm * 16 + (lane & 15)) * 32 + (lane >> 4) * 8]);
    #pragma unroll
    for (int p = 0; p < 4; ++p) {
      bf16x8 bfr[2];
      #pragma unroll
      for (int fn = 0; fn < 2; ++fn)
        bfr[fn] = *reinterpret_cast<const bf16x8*>(
            &lds[buf][PLDS_A + p * 2048 + (wc * 32 + fn * 16 + (lane & 15)) * 32 + (lane >> 4) * 8]);
      #pragma unroll
      for (int fm = 0; fm < 4; ++fm)
        #pragma unroll
        for (int fn = 0; fn < 2; ++fn)
          acc[p][fm][fn] = __builtin_amdgcn_mfma_f32_16x16x32_bf16(
              af[fm], bfr[fn], acc[p][fm][fn], 0, 0, 0);
    }
    __syncthreads();
  }

  // epilogue: dt = softplus(zdt); vlog = dt*A_log; u = dt*zB*zV; c = zC
  // nontemporal: these 201 MB of streaming writes must not evict W4 from L2.
  #pragma unroll
  for (int fn = 0; fn < 2; ++fn) {
    const int n = n0 + wc * 32 + fn * 16 + (lane & 15);
    const float vbdt = b_dt[n], vbB = b_B[n], vbC = b_C[n], vbV = b_V[n];
    const float al = A_log[n];
    #pragma unroll
    for (int fm = 0; fm < 4; ++fm) {
      const int mbase = m0 + wr * 64 + fm * 16 + (lane >> 4) * 4;
      #pragma unroll
      for (int r = 0; r < 4; ++r) {
        const size_t off = (size_t)(mbase + r) * NCH + n;
        const float zdt = acc[0][fm][fn][r] + vbdt;
        const float zB  = acc[1][fm][fn][r] + vbB;
        const float zC  = acc[2][fm][fn][r] + vbC;
        const float zV  = acc[3][fm][fn][r] + vbV;
        const float dt = (zdt > 15.f) ? zdt : __logf(1.f + __expf(zdt));
        __builtin_nontemporal_store(f2bf(dt * al), &vlog[off]);
        __builtin_nontemporal_store(f2bf(dt * zB * zV), &u_out[off]);
        __builtin_nontemporal_store(f2bf(zC), &c_out[off]);
      }
    }
  }
}

// ---------------- chunked parallel scan ----------------
// block = 64 channels x 16 s-chunks (16 waves, 1024 thr). grid = (128 ch-groups, 2 batches)
// pass A: per-chunk local scan (h0=0) -> summaries in LDS
// pass B: wave 0 serially combines 16 summaries per channel -> per-chunk h0
// pass C: re-scan with true h0, y = C*h written in place over C.
#define SCH 16
#define CSTEPS 128
__global__ __launch_bounds__(1024) void scan_kernel(
    const unsigned short* __restrict__ vlog,
    const unsigned short* __restrict__ u_in,
    unsigned short* cy)
{
  __shared__ float Ap[SCH][64], He[SCH][64], H0[SCH][64];
  const int lane = threadIdx.x & 63;
  const int w = threadIdx.x >> 6;
  const int c = blockIdx.x * 64 + lane;
  const size_t base = (size_t)blockIdx.y * SEQL * NCH + (size_t)(w * CSTEPS) * NCH + c;

  // pass A
  {
    const unsigned short* ap = vlog + base;
    const unsigned short* up = u_in + base;
    float h = 0.f, vsum = 0.f;
    #pragma unroll 1
    for (int s = 0; s < CSTEPS; s += 8) {
      float av[8], uv[8];
      #pragma unroll
      for (int i = 0; i < 8; ++i) {
        av[i] = bf2f(ap[(size_t)(s + i) * NCH]);
        uv[i] = bf2f(up[(size_t)(s + i) * NCH]);
      }
      #pragma unroll
      for (int i = 0; i < 8; ++i) {
        vsum += av[i];
        h = fmaf(__expf(av[i]), h, uv[i]);
      }
    }
    Ap[w][lane] = __expf(vsum);
    He[w][lane] = h;
  }
  __syncthreads();
  // pass B (wave 0)
  if (w == 0) {
    float run = 0.f;
    #pragma unroll
    for (int j = 0; j < SCH; ++j) {
      H0[j][lane] = run;
      run = fmaf(Ap[j][lane], run, He[j][lane]);
    }
  }
  __syncthreads();
  // pass C
  {
    const unsigned short* ap = vlog + base;
    const unsigned short* up = u_in + base;
    unsigned short* cp = cy + base;
    float h = H0[w][lane];
    #pragma unroll 1
    for (int s = 0; s < CSTEPS; s += 8) {
      float av[8], uv[8], cv[8];
      #pragma unroll
      for (int i = 0; i < 8; ++i) {
        av[i] = bf2f(ap[(size_t)(s + i) * NCH]);
        uv[i] = bf2f(up[(size_t)(s + i) * NCH]);
        cv[i] = bf2f(cp[(size_t)(s + i) * NCH]);
      }
      #pragma unroll
      for (int i = 0; i < 8; ++i) {
        h = fmaf(__expf(av[i]), h, uv[i]);
        cv[i] *= h;
      }
      #pragma unroll
      for (int i = 0; i < 8; ++i)
        __builtin_nontemporal_store(f2bf(cv[i]), &cp[(size_t)(s + i) * NCH]);
    }
  }
}

// ---------------- output projection, split-K: partial[ks][m][d] ----------------
// grid dim3(32 m, 8 d, 8 ks): same-y-panel blocks (same m,ks; d varies) have ids
// differing by 32 (32%8==0) -> same XCD -> y fetched once per XCD panel.
#define OLDS_A 4096   // 128*32
#define OLDS_B 2048   // 64*32
__global__ __launch_bounds__(256) void outproj_kernel(
    const unsigned short* __restrict__ yb,    // [4096][8192] bf16
    const unsigned short* __restrict__ wout,  // [512][8192] bf16
    float* __restrict__ partial)              // [KS][4096][512] f32
{
  __shared__ __align__(16) unsigned short lds[2][OLDS_A + OLDS_B];
  const int tid = threadIdx.x;
  const int lane = tid & 63;
  const int wave = tid >> 6;
  const int wr = wave >> 1, wc = wave & 1;
  const int m0 = blockIdx.x * 128;
  const int d0 = blockIdx.y * 64;
  const int kbase = blockIdx.z * (NCH / KS);   // 1024 per split

  auto stage = [&](int buf, int kt) {
    const int k0 = kbase + kt * 32;
    #pragma unroll
    for (int i = 0; i < 2; ++i) {
      int c = i * 256 + tid;
      int row = c >> 2, q = c & 3;
      const unsigned short* g = yb + (size_t)(m0 + row) * NCH + k0 + q * 8;
      __builtin_amdgcn_global_load_lds(
          (const __attribute__((address_space(1))) void*)g,
          (__attribute__((address_space(3))) void*)&lds[buf][c * 8], 16, 0, 0);
    }
    {
      int row = tid >> 2, q = tid & 3;
      const unsigned short* g = wout + (size_t)(d0 + row) * NCH + k0 + q * 8;
      __builtin_amdgcn_global_load_lds(
          (const __attribute__((address_space(1))) void*)g,
          (__attribute__((address_space(3))) void*)&lds[buf][OLDS_A + tid * 8], 16, 0, 0);
    }
  };

  f32x4 acc[4][2];
  #pragma unroll
  for (int fm = 0; fm < 4; ++fm)
    #pragma unroll
    for (int fn = 0; fn < 2; ++fn) acc[fm][fn] = (f32x4){0.f, 0.f, 0.f, 0.f};

  stage(0, 0);
  __syncthreads();
  constexpr int NKT = (NCH / KS) / 32;   // 32
  #pragma unroll 1
  for (int kt = 0; kt < NKT; ++kt) {
    const int buf = kt & 1;
    if (kt + 1 < NKT) stage(buf ^ 1, kt + 1);
    bf16x8 af[4], bfr[2];
    #pragma unroll
    for (int fm = 0; fm < 4; ++fm)
      af[fm] = *reinterpret_cast<const bf16x8*>(
          &lds[buf][(wr * 64 + fm * 16 + (lane & 15)) * 32 + (lane >> 4) * 8]);
    #pragma unroll
    for (int fn = 0; fn < 2; ++fn)
      bfr[fn] = *reinterpret_cast<const bf16x8*>(
          &lds[buf][OLDS_A + (wc * 32 + fn * 16 + (lane & 15)) * 32 + (lane >> 4) * 8]);
    #pragma unroll
    for (int fm = 0; fm < 4; ++fm)
      #pragma unroll
      for (int fn = 0; fn < 2; ++fn)
        acc[fm][fn] = __builtin_amdgcn_mfma_f32_16x16x32_bf16(
            af[fm], bfr[fn], acc[fm][fn], 0, 0, 0);
    __syncthreads();
  }

  float* pout = partial + (size_t)blockIdx.z * MTOT * DIMK;
  #pragma unroll
  for (int fn = 0; fn < 2; ++fn) {
    const int d = d0 + wc * 32 + fn * 16 + (lane & 15);
    #pragma unroll
    for (int fm = 0; fm < 4; ++fm) {
      const int mbase = m0 + wr * 64 + fm * 16 + (lane >> 4) * 4;
      #pragma unroll
      for (int r = 0; r < 4; ++r)
        __builtin_nontemporal_store(acc[fm][fn][r],
                                    &pout[(size_t)(mbase + r) * DIMK + d]);
    }
  }
}

// ---------------- split-K reduce + bias ----------------
__global__ __launch_bounds__(256) void reduce_kernel(
    const float* __restrict__ p, const float* __restrict__ bias,
    float* __restrict__ out)
{
  const int i = blockIdx.x * 256 + threadIdx.x;   // float4 index, 524288 total
  const float4* p4 = reinterpret_cast<const float4*>(p);
  float4 s = p4[i];
  #pragma unroll
  for (int k = 1; k < KS; ++k) {
    float4 t = p4[(size_t)k * (MTOT * DIMK / 4) + i];
    s.x += t.x; s.y += t.y; s.z += t.z; s.w += t.w;
  }
  const float4 b = reinterpret_cast<const float4*>(bias)[i & 127];
  s.x += b.x; s.y += b.y; s.z += b.z; s.w += b.w;
  reinterpret_cast<float4*>(out)[i] = s;
}

extern "C" void kernel_launch(void* const* d_in, const int* in_sizes, int n_in,
                              void* d_out, int out_size, void* d_ws, size_t ws_size,
                              hipStream_t stream) {
  const float* x    = (const float*)d_in[0];
  const float* Wdt  = (const float*)d_in[1];
  const float* bdt  = (const float*)d_in[2];
  const float* WB   = (const float*)d_in[3];
  const float* bB   = (const float*)d_in[4];
  const float* WC   = (const float*)d_in[5];
  const float* bC   = (const float*)d_in[6];
  const float* WV   = (const float*)d_in[7];
  const float* bV   = (const float*)d_in[8];
  const float* Alog = (const float*)d_in[9];
  const float* Wout = (const float*)d_in[10];
  const float* bout = (const float*)d_in[11];
  float* out = (float*)d_out;

  char* ws = (char*)d_ws;
  unsigned short* woutb = (unsigned short*)(ws);               // 8 MiB
  unsigned short* xb    = (unsigned short*)(ws + 8388608);     // 4 MiB
  unsigned short* w4    = (unsigned short*)(ws + 12582912);    // 32 MiB
  char* dyn = ws + 46137344;
  const size_t csz = (size_t)MTOT * NCH * 2;                   // 64 MiB
  unsigned short* vlog = (unsigned short*)(dyn);
  unsigned short* u_b  = (unsigned short*)(dyn + csz);
  unsigned short* cy   = (unsigned short*)(dyn + 2 * csz);
  float* partial = (float*)vlog;   // alias: vlog dead after scan; KS*4096*512*4 = 64 MiB

  cvt_kernel<<<1024, 256, 0, stream>>>(x, xb, 262144);
  cvt_kernel<<<2048, 256, 0, stream>>>(Wdt, w4 + 0 * 4194304, 524288);
  cvt_kernel<<<2048, 256, 0, stream>>>(WB,  w4 + 1 * 4194304, 524288);
  cvt_kernel<<<2048, 256, 0, stream>>>(WC,  w4 + 2 * 4194304, 524288);
  cvt_kernel<<<2048, 256, 0, stream>>>(WV,  w4 + 3 * 4194304, 524288);
  cvt_kernel<<<2048, 256, 0, stream>>>(Wout, woutb, 524288);

  proj_kernel<<<dim3(NCH / 64, MTOT / 128), 256, 0, stream>>>(
      xb, w4, bdt, bB, bC, bV, Alog, vlog, u_b, cy);
  scan_kernel<<<dim3(NCH / 64, 2), 1024, 0, stream>>>(vlog, u_b, cy);
  outproj_kernel<<<dim3(MTOT / 128, DIMK / 64, KS), 256, 0, stream>>>(
      cy, woutb, partial);
  reduce_kernel<<<MTOT * DIMK / 4 / 256, 256, 0, stream>>>(partial, bout, out);
}

// Round 4
// 495.651 us; speedup vs baseline: 1.4099x; 1.1990x over previous
//
#include <hip/hip_runtime.h>

#define DIMK 512
#define NCH  8192
#define MTOT 4096   // BATCH*SEQ = 2*2048
#define SEQL 2048
#define KS   8      // outproj K-splits

typedef __attribute__((ext_vector_type(8))) short bf16x8;
typedef __attribute__((ext_vector_type(4))) float f32x4;

__device__ __forceinline__ unsigned short f2bf(float f) {
  unsigned int u = __float_as_uint(f);
  u += 0x7fffu + ((u >> 16) & 1u);
  return (unsigned short)(u >> 16);
}
__device__ __forceinline__ float bf2f(unsigned short v) {
  return __uint_as_float(((unsigned int)v) << 16);
}

// ---------------- fused f32 -> bf16 convert, all 6 tensors in one launch ----------------
struct CvtArgs {
  const float* src[6];
  unsigned short* dst[6];
  int cum[7];   // cumulative item counts (1 item = 8 elems)
};
__global__ __launch_bounds__(256) void cvt_all_kernel(CvtArgs a, int tot) {
  const int stride = gridDim.x * 256;
  for (int i = blockIdx.x * 256 + threadIdx.x; i < tot; i += stride) {
    int s = 0;
    while (i >= a.cum[s + 1]) ++s;
    const int j = i - a.cum[s];
    const float4* sp = reinterpret_cast<const float4*>(a.src[s]);
    float4 v0 = sp[2 * j], v1 = sp[2 * j + 1];
    union { unsigned short us[8]; uint4 v; } o;
    o.us[0] = f2bf(v0.x); o.us[1] = f2bf(v0.y); o.us[2] = f2bf(v0.z); o.us[3] = f2bf(v0.w);
    o.us[4] = f2bf(v1.x); o.us[5] = f2bf(v1.y); o.us[6] = f2bf(v1.z); o.us[7] = f2bf(v1.w);
    reinterpret_cast<uint4*>(a.dst[s])[j] = o.v;
  }
}

// swizzle: logical (row, q) lives at linear slot (row, q ^ ((row>>2)&3)); q = 16B unit
__device__ __forceinline__ int swz(int row, int q) { return q ^ ((row >> 2) & 3); }

// ---------------- fused 4-way projection GEMM + SSM epilogue ----------------
// 3-buffer counted-vmcnt pipeline (T3/T4-lite) + swizzled LDS (T2) + setprio (T5)
#define PLDS_A 4096            // 128*32 elems
#define PLDS_W 8192            // 4*64*32 elems
#define PLDS   (PLDS_A + PLDS_W)
__global__ __launch_bounds__(256) void proj_kernel(
    const unsigned short* __restrict__ xb,
    const unsigned short* __restrict__ w4,
    const float* __restrict__ b_dt, const float* __restrict__ b_B,
    const float* __restrict__ b_C, const float* __restrict__ b_V,
    const float* __restrict__ A_log,
    unsigned short* __restrict__ vlog,   // [4096][8192] bf16: dt*A_log
    unsigned short* __restrict__ u_out,  // [4096][8192] bf16: dt*zB*zV
    unsigned short* __restrict__ c_out)  // [4096][8192] bf16: zC
{
  __shared__ __align__(16) unsigned short lds[3][PLDS];
  const int tid = threadIdx.x;
  const int lane = tid & 63;
  const int wave = tid >> 6;
  const int wr = wave >> 1, wc = wave & 1;
  const int n0 = blockIdx.x * 64;
  const int m0 = blockIdx.y * 128;

  // stage: LDS dest linear, global source pre-swizzled (rule #21)
  auto stage = [&](int buf, int kt) {
    const int k0 = kt * 32;
    #pragma unroll
    for (int i = 0; i < 2; ++i) {            // A tile: 128x32
      int c = i * 256 + tid;
      int row = c >> 2, q = c & 3;
      const unsigned short* g = xb + (size_t)(m0 + row) * DIMK + k0 + swz(row, q) * 8;
      __builtin_amdgcn_global_load_lds(
          (const __attribute__((address_space(1))) void*)g,
          (__attribute__((address_space(3))) void*)&lds[buf][c * 8], 16, 0, 0);
    }
    #pragma unroll
    for (int p = 0; p < 4; ++p) {            // W tiles: 4 x 64x32
      int row = tid >> 2, q = tid & 3;
      const unsigned short* g = w4 + ((size_t)p * NCH + n0 + row) * DIMK + k0 + swz(row, q) * 8;
      __builtin_amdgcn_global_load_lds(
          (const __attribute__((address_space(1))) void*)g,
          (__attribute__((address_space(3))) void*)&lds[buf][PLDS_A + p * 2048 + tid * 8], 16, 0, 0);
    }
  };

  f32x4 acc[4][4][2];
  #pragma unroll
  for (int p = 0; p < 4; ++p)
    #pragma unroll
    for (int fm = 0; fm < 4; ++fm)
      #pragma unroll
      for (int fn = 0; fn < 2; ++fn)
        acc[p][fm][fn] = (f32x4){0.f, 0.f, 0.f, 0.f};

  stage(0, 0);
  stage(1, 1);
  constexpr int NKT = DIMK / 32;   // 16
  #pragma unroll 1
  for (int kt = 0; kt < NKT; ++kt) {
    const int buf = kt % 3;
    // counted wait: tile kt's 6 loads done; tile kt+1's 6 may stay in flight
    if (kt < NKT - 1) asm volatile("s_waitcnt vmcnt(6)" ::: "memory");
    else              asm volatile("s_waitcnt vmcnt(0)" ::: "memory");
    __builtin_amdgcn_s_barrier();
    if (kt + 2 < NKT) stage((kt + 2) % 3, kt + 2);   // issue-early, 2 ahead

    const int arow = wr * 64 + (lane & 15);
    const int qq = lane >> 4;
    bf16x8 af[4];
    #pragma unroll
    for (int fm = 0; fm < 4; ++fm) {
      const int r = arow + fm * 16;
      af[fm] = *reinterpret_cast<const bf16x8*>(&lds[buf][r * 32 + swz(r, qq) * 8]);
    }
    #pragma unroll
    for (int p = 0; p < 4; ++p) {
      bf16x8 bfr[2];
      #pragma unroll
      for (int fn = 0; fn < 2; ++fn) {
        const int r = wc * 32 + fn * 16 + (lane & 15);
        bfr[fn] = *reinterpret_cast<const bf16x8*>(
            &lds[buf][PLDS_A + p * 2048 + r * 32 + swz(r, qq) * 8]);
      }
      __builtin_amdgcn_s_setprio(1);
      #pragma unroll
      for (int fm = 0; fm < 4; ++fm)
        #pragma unroll
        for (int fn = 0; fn < 2; ++fn)
          acc[p][fm][fn] = __builtin_amdgcn_mfma_f32_16x16x32_bf16(
              af[fm], bfr[fn], acc[p][fm][fn], 0, 0, 0);
      __builtin_amdgcn_s_setprio(0);
    }
    // my ds_reads of buf done before anyone re-stages it (next iter's barrier)
    asm volatile("s_waitcnt lgkmcnt(0)" ::: "memory");
  }

  // epilogue: plain stores (NT regressed: 32B partial-line RMW at HBM)
  #pragma unroll
  for (int fn = 0; fn < 2; ++fn) {
    const int n = n0 + wc * 32 + fn * 16 + (lane & 15);
    const float vbdt = b_dt[n], vbB = b_B[n], vbC = b_C[n], vbV = b_V[n];
    const float al = A_log[n];
    #pragma unroll
    for (int fm = 0; fm < 4; ++fm) {
      const int mbase = m0 + wr * 64 + fm * 16 + (lane >> 4) * 4;
      #pragma unroll
      for (int r = 0; r < 4; ++r) {
        const size_t off = (size_t)(mbase + r) * NCH + n;
        const float zdt = acc[0][fm][fn][r] + vbdt;
        const float zB  = acc[1][fm][fn][r] + vbB;
        const float zC  = acc[2][fm][fn][r] + vbC;
        const float zV  = acc[3][fm][fn][r] + vbV;
        const float dt = (zdt > 15.f) ? zdt : __logf(1.f + __expf(zdt));
        vlog[off]  = f2bf(dt * al);
        u_out[off] = f2bf(dt * zB * zV);
        c_out[off] = f2bf(zC);
      }
    }
  }
}

// ---------------- chunked parallel scan (unchanged) ----------------
#define SCH 16
#define CSTEPS 128
__global__ __launch_bounds__(1024) void scan_kernel(
    const unsigned short* __restrict__ vlog,
    const unsigned short* __restrict__ u_in,
    unsigned short* cy)
{
  __shared__ float Ap[SCH][64], He[SCH][64], H0[SCH][64];
  const int lane = threadIdx.x & 63;
  const int w = threadIdx.x >> 6;
  const int c = blockIdx.x * 64 + lane;
  const size_t base = (size_t)blockIdx.y * SEQL * NCH + (size_t)(w * CSTEPS) * NCH + c;

  {
    const unsigned short* ap = vlog + base;
    const unsigned short* up = u_in + base;
    float h = 0.f, vsum = 0.f;
    #pragma unroll 1
    for (int s = 0; s < CSTEPS; s += 8) {
      float av[8], uv[8];
      #pragma unroll
      for (int i = 0; i < 8; ++i) {
        av[i] = bf2f(ap[(size_t)(s + i) * NCH]);
        uv[i] = bf2f(up[(size_t)(s + i) * NCH]);
      }
      #pragma unroll
      for (int i = 0; i < 8; ++i) {
        vsum += av[i];
        h = fmaf(__expf(av[i]), h, uv[i]);
      }
    }
    Ap[w][lane] = __expf(vsum);
    He[w][lane] = h;
  }
  __syncthreads();
  if (w == 0) {
    float run = 0.f;
    #pragma unroll
    for (int j = 0; j < SCH; ++j) {
      H0[j][lane] = run;
      run = fmaf(Ap[j][lane], run, He[j][lane]);
    }
  }
  __syncthreads();
  {
    const unsigned short* ap = vlog + base;
    const unsigned short* up = u_in + base;
    unsigned short* cp = cy + base;
    float h = H0[w][lane];
    #pragma unroll 1
    for (int s = 0; s < CSTEPS; s += 8) {
      float av[8], uv[8], cv[8];
      #pragma unroll
      for (int i = 0; i < 8; ++i) {
        av[i] = bf2f(ap[(size_t)(s + i) * NCH]);
        uv[i] = bf2f(up[(size_t)(s + i) * NCH]);
        cv[i] = bf2f(cp[(size_t)(s + i) * NCH]);
      }
      #pragma unroll
      for (int i = 0; i < 8; ++i) {
        h = fmaf(__expf(av[i]), h, uv[i]);
        cv[i] *= h;
      }
      #pragma unroll
      for (int i = 0; i < 8; ++i)
        __builtin_nontemporal_store(f2bf(cv[i]), &cp[(size_t)(s + i) * NCH]);
    }
  }
}

// ---------------- output projection, split-K, same pipeline ----------------
#define OLDS_A 4096   // 128*32
#define OLDS_B 2048   // 64*32
#define OLDS   (OLDS_A + OLDS_B)
__global__ __launch_bounds__(256) void outproj_kernel(
    const unsigned short* __restrict__ yb,    // [4096][8192] bf16
    const unsigned short* __restrict__ wout,  // [512][8192] bf16
    float* __restrict__ partial)              // [KS][4096][512] f32
{
  __shared__ __align__(16) unsigned short lds[3][OLDS];
  const int tid = threadIdx.x;
  const int lane = tid & 63;
  const int wave = tid >> 6;
  const int wr = wave >> 1, wc = wave & 1;
  const int m0 = blockIdx.x * 128;
  const int d0 = blockIdx.y * 64;
  const int kbase = blockIdx.z * (NCH / KS);   // 1024 per split

  auto stage = [&](int buf, int kt) {
    const int k0 = kbase + kt * 32;
    #pragma unroll
    for (int i = 0; i < 2; ++i) {
      int c = i * 256 + tid;
      int row = c >> 2, q = c & 3;
      const unsigned short* g = yb + (size_t)(m0 + row) * NCH + k0 + swz(row, q) * 8;
      __builtin_amdgcn_global_load_lds(
          (const __attribute__((address_space(1))) void*)g,
          (__attribute__((address_space(3))) void*)&lds[buf][c * 8], 16, 0, 0);
    }
    {
      int row = tid >> 2, q = tid & 3;
      const unsigned short* g = wout + (size_t)(d0 + row) * NCH + k0 + swz(row, q) * 8;
      __builtin_amdgcn_global_load_lds(
          (const __attribute__((address_space(1))) void*)g,
          (__attribute__((address_space(3))) void*)&lds[buf][OLDS_A + tid * 8], 16, 0, 0);
    }
  };

  f32x4 acc[4][2];
  #pragma unroll
  for (int fm = 0; fm < 4; ++fm)
    #pragma unroll
    for (int fn = 0; fn < 2; ++fn) acc[fm][fn] = (f32x4){0.f, 0.f, 0.f, 0.f};

  stage(0, 0);
  stage(1, 1);
  constexpr int NKT = (NCH / KS) / 32;   // 32
  #pragma unroll 1
  for (int kt = 0; kt < NKT; ++kt) {
    const int buf = kt % 3;
    if (kt < NKT - 1) asm volatile("s_waitcnt vmcnt(3)" ::: "memory");
    else              asm volatile("s_waitcnt vmcnt(0)" ::: "memory");
    __builtin_amdgcn_s_barrier();
    if (kt + 2 < NKT) stage((kt + 2) % 3, kt + 2);

    const int qq = lane >> 4;
    bf16x8 af[4], bfr[2];
    #pragma unroll
    for (int fm = 0; fm < 4; ++fm) {
      const int r = wr * 64 + fm * 16 + (lane & 15);
      af[fm] = *reinterpret_cast<const bf16x8*>(&lds[buf][r * 32 + swz(r, qq) * 8]);
    }
    #pragma unroll
    for (int fn = 0; fn < 2; ++fn) {
      const int r = wc * 32 + fn * 16 + (lane & 15);
      bfr[fn] = *reinterpret_cast<const bf16x8*>(
          &lds[buf][OLDS_A + r * 32 + swz(r, qq) * 8]);
    }
    __builtin_amdgcn_s_setprio(1);
    #pragma unroll
    for (int fm = 0; fm < 4; ++fm)
      #pragma unroll
      for (int fn = 0; fn < 2; ++fn)
        acc[fm][fn] = __builtin_amdgcn_mfma_f32_16x16x32_bf16(
            af[fm], bfr[fn], acc[fm][fn], 0, 0, 0);
    __builtin_amdgcn_s_setprio(0);
    asm volatile("s_waitcnt lgkmcnt(0)" ::: "memory");
  }

  float* pout = partial + (size_t)blockIdx.z * MTOT * DIMK;
  #pragma unroll
  for (int fn = 0; fn < 2; ++fn) {
    const int d = d0 + wc * 32 + fn * 16 + (lane & 15);
    #pragma unroll
    for (int fm = 0; fm < 4; ++fm) {
      const int mbase = m0 + wr * 64 + fm * 16 + (lane >> 4) * 4;
      #pragma unroll
      for (int r = 0; r < 4; ++r)
        __builtin_nontemporal_store(acc[fm][fn][r],
                                    &pout[(size_t)(mbase + r) * DIMK + d]);
    }
  }
}

// ---------------- split-K reduce + bias ----------------
__global__ __launch_bounds__(256) void reduce_kernel(
    const float* __restrict__ p, const float* __restrict__ bias,
    float* __restrict__ out)
{
  const int i = blockIdx.x * 256 + threadIdx.x;   // float4 index, 524288 total
  const float4* p4 = reinterpret_cast<const float4*>(p);
  float4 s = p4[i];
  #pragma unroll
  for (int k = 1; k < KS; ++k) {
    float4 t = p4[(size_t)k * (MTOT * DIMK / 4) + i];
    s.x += t.x; s.y += t.y; s.z += t.z; s.w += t.w;
  }
  const float4 b = reinterpret_cast<const float4*>(bias)[i & 127];
  s.x += b.x; s.y += b.y; s.z += b.z; s.w += b.w;
  reinterpret_cast<float4*>(out)[i] = s;
}

extern "C" void kernel_launch(void* const* d_in, const int* in_sizes, int n_in,
                              void* d_out, int out_size, void* d_ws, size_t ws_size,
                              hipStream_t stream) {
  const float* x    = (const float*)d_in[0];
  const float* Wdt  = (const float*)d_in[1];
  const float* bdt  = (const float*)d_in[2];
  const float* WB   = (const float*)d_in[3];
  const float* bB   = (const float*)d_in[4];
  const float* WC   = (const float*)d_in[5];
  const float* bC   = (const float*)d_in[6];
  const float* WV   = (const float*)d_in[7];
  const float* bV   = (const float*)d_in[8];
  const float* Alog = (const float*)d_in[9];
  const float* Wout = (const float*)d_in[10];
  const float* bout = (const float*)d_in[11];
  float* out = (float*)d_out;

  char* ws = (char*)d_ws;
  unsigned short* woutb = (unsigned short*)(ws);               // 8 MiB
  unsigned short* xb    = (unsigned short*)(ws + 8388608);     // 4 MiB
  unsigned short* w4    = (unsigned short*)(ws + 12582912);    // 32 MiB
  char* dyn = ws + 46137344;
  const size_t csz = (size_t)MTOT * NCH * 2;                   // 64 MiB
  unsigned short* vlog = (unsigned short*)(dyn);
  unsigned short* u_b  = (unsigned short*)(dyn + csz);
  unsigned short* cy   = (unsigned short*)(dyn + 2 * csz);
  float* partial = (float*)vlog;   // alias: vlog dead after scan; KS*4096*512*4 = 64 MiB

  CvtArgs ca;
  ca.src[0] = x;    ca.dst[0] = xb;
  ca.src[1] = Wdt;  ca.dst[1] = w4 + 0 * 4194304;
  ca.src[2] = WB;   ca.dst[2] = w4 + 1 * 4194304;
  ca.src[3] = WC;   ca.dst[3] = w4 + 2 * 4194304;
  ca.src[4] = WV;   ca.dst[4] = w4 + 3 * 4194304;
  ca.src[5] = Wout; ca.dst[5] = woutb;
  ca.cum[0] = 0;        ca.cum[1] = 262144;  ca.cum[2] = 786432;
  ca.cum[3] = 1310720;  ca.cum[4] = 1835008; ca.cum[5] = 2359296;
  ca.cum[6] = 2883584;
  cvt_all_kernel<<<2048, 256, 0, stream>>>(ca, 2883584);

  proj_kernel<<<dim3(NCH / 64, MTOT / 128), 256, 0, stream>>>(
      xb, w4, bdt, bB, bC, bV, Alog, vlog, u_b, cy);
  scan_kernel<<<dim3(NCH / 64, 2), 1024, 0, stream>>>(vlog, u_b, cy);
  outproj_kernel<<<dim3(MTOT / 128, DIMK / 64, KS), 256, 0, stream>>>(
      cy, woutb, partial);
  reduce_kernel<<<MTOT * DIMK / 4 / 256, 256, 0, stream>>>(partial, bout, out);
}